// Round 10
// baseline (225.451 us; speedup 1.0000x reference)
//
#include <hip/hip_runtime.h>
#include <hip/hip_bf16.h>

// SNN IF scan, T=4. Memory-bound: 134 MB in + 134 MB out (~43 us at copy
// rate). Ten-round findings: load policy is THE lever (nt ~67 us vs plain
// ~81 us in every structure — plain loads thrash/serialize on L1 allocate;
// nt bypasses). Store policy neutral (R9). Batch depth ~3 us (R4->R6).
// R10 tests the last untouched lever: TLP. Drop the register batch entirely
// (UNROLL=1 -> ~16 data VGPRs), keep nt loads, launch 8192 blocks ->
// 8 waves/SIMD (32 waves/CU, vs ~12 at R6's VGPR~140). MLP now comes from
// wave count (copy-ubench shape: 32 waves x 4 KB outstanding >= 128 KB/CU)
// instead of per-wave batching. No sched_barrier, no fences — they never
// reliably pinned anything anyway (R7/R8).

#define T_STEPS 4

typedef float vfloat4 __attribute__((ext_vector_type(4)));

__global__ __launch_bounds__(256) void IF_18622978195596_kernel(
    const vfloat4* __restrict__ x, const float* __restrict__ thresh_p,
    vfloat4* __restrict__ out, int n4) {
    const int i = blockIdx.x * 256 + threadIdx.x;   // grid covers n4 exactly
    const float th = *thresh_p;

    // 4 independent nt loads (compiler batches these naturally at UNROLL=1:
    // consume order == issue order, 16 data VGPRs).
    vfloat4 xv[T_STEPS];
#pragma unroll
    for (int t = 0; t < T_STEPS; ++t)
        xv[t] = __builtin_nontemporal_load(&x[(size_t)t * n4 + i]);

    vfloat4 mem = {0.5f * th, 0.5f * th, 0.5f * th, 0.5f * th};
#pragma unroll
    for (int t = 0; t < T_STEPS; ++t) {
        mem += xv[t];
        vfloat4 s;
        s.x = (mem.x >= th) ? th : 0.0f;
        s.y = (mem.y >= th) ? th : 0.0f;
        s.z = (mem.z >= th) ? th : 0.0f;
        s.w = (mem.w >= th) ? th : 0.0f;
        mem -= s;
        __builtin_nontemporal_store(s, &out[(size_t)t * n4 + i]);
    }
}

extern "C" void kernel_launch(void* const* d_in, const int* in_sizes, int n_in,
                              void* d_out, int out_size, void* d_ws, size_t ws_size,
                              hipStream_t stream) {
    const float* x = (const float*)d_in[0];
    const float* thresh = (const float*)d_in[1];
    float* out = (float*)d_out;

    int total = in_sizes[0];              // 33,554,432 floats
    int n_per_t = total / T_STEPS;        // 8,388,608 neurons
    int n4 = n_per_t / 4;                 // 2,097,152 vfloat4 per timestep

    int block = 256;
    int grid = n4 / block;                // 8192 blocks, exact
    IF_18622978195596_kernel<<<grid, block, 0, stream>>>(
        (const vfloat4*)x, thresh, (vfloat4*)out, n4);
}